// Round 6
// baseline (310.746 us; speedup 1.0000x reference)
//
#include <hip/hip_runtime.h>
#include <hip/hip_bf16.h>
#include <stdint.h>

// ---- problem constants ----
#define BB 64
#define NN 320
#define CC 768
#define HH 12
#define DH 64
#define NC3 2304
#define MROWS (BB*NN)   // 20480

typedef __attribute__((ext_vector_type(8))) short short8;
typedef __attribute__((ext_vector_type(4))) float f32x4;
typedef __attribute__((ext_vector_type(8))) __bf16 bf16x8;

union BF8U { short8 s; bf16x8 b; };
static __device__ __forceinline__ bf16x8 asbf(short8 v){ BF8U u; u.s = v; return u.b; }

#define MFMA16(a,b,c) __builtin_amdgcn_mfma_f32_16x16x32_bf16((a),(b),(c),0,0,0)

// async global->LDS, 16B per lane; LDS dest = wave-uniform base + lane*16
static __device__ __forceinline__ void gload16(const void* g, void* l){
  __builtin_amdgcn_global_load_lds(
      (const __attribute__((address_space(1))) void*)g,
      (__attribute__((address_space(3))) void*)l, 16, 0, 0);
}

// ------------------------------------------------------------------
// Kernel 0a: tiled transpose+convert  outT[n][k] = bf16(in[k][n])
// ------------------------------------------------------------------
__global__ __launch_bounds__(256) void convert_wT(
    const float* __restrict__ in, __hip_bfloat16* __restrict__ outT,
    int K, int Nc)
{
  __shared__ __hip_bfloat16 t[64][72];   // +8 pad
  const int n0 = blockIdx.x * 64, k0 = blockIdx.y * 64;
  const int tid = threadIdx.x;
  const int tx = tid & 15, ty = tid >> 4;          // 16 x 16

  #pragma unroll
  for (int i = 0; i < 4; ++i){
    int kl = ty + i * 16;
    float4 v = *reinterpret_cast<const float4*>(&in[(size_t)(k0 + kl) * Nc + n0 + tx * 4]);
    t[tx*4+0][kl] = __float2bfloat16(v.x);
    t[tx*4+1][kl] = __float2bfloat16(v.y);
    t[tx*4+2][kl] = __float2bfloat16(v.z);
    t[tx*4+3][kl] = __float2bfloat16(v.w);
  }
  __syncthreads();
  #pragma unroll
  for (int j = 0; j < 2; ++j){
    int nl = (tid >> 3) + j * 32;
    int kl = (tid & 7) * 8;
    short8 v = *reinterpret_cast<const short8*>(&t[nl][kl]);
    *reinterpret_cast<short8*>(&outT[(size_t)(n0 + nl) * K + k0 + kl]) = v;
  }
}

// ------------------------------------------------------------------
// Kernel 0b: convert x fp32 -> bf16 (row-major, same layout)
// ------------------------------------------------------------------
__global__ __launch_bounds__(256) void convert_x(
    const float* __restrict__ X, __hip_bfloat16* __restrict__ Xb)
{
  size_t i = ((size_t)blockIdx.x * 256 + threadIdx.x) * 8;
  float4 a = *reinterpret_cast<const float4*>(&X[i]);
  float4 b = *reinterpret_cast<const float4*>(&X[i + 4]);
  __hip_bfloat16 t[8] = {__float2bfloat16(a.x), __float2bfloat16(a.y),
                         __float2bfloat16(a.z), __float2bfloat16(a.w),
                         __float2bfloat16(b.x), __float2bfloat16(b.y),
                         __float2bfloat16(b.z), __float2bfloat16(b.w)};
  *reinterpret_cast<short8*>(&Xb[i]) = *reinterpret_cast<const short8*>(t);
}

// ------------------------------------------------------------------
// GEMM geometry: 256x256 tile, BK=64, 8 waves (512 thr) as 2M x 4N.
// Per-wave output 128x64. Double-buffered 128 KB dynamic LDS.
// XOR-swizzle both-sides (rule #21).
// Sync: T4 counted vmcnt — per K-iter each wave issues 8 gload_lds;
// s_waitcnt vmcnt(8) waits for the OLDEST 8 (= current tile) while the
// next tile's 8 stay in flight across raw s_barriers. No vmcnt(0) drain
// in the main loop (the round-4/5 flatline was __syncthreads' forced
// vmcnt(0) serializing stage latency with compute).
// ------------------------------------------------------------------
#define BM 256
#define BN 256
#define BK 64
#define NT (CC/BK)        // 12
#define ABUF (BM*BK)      // 16384 elems per A buffer
#define BBUF (BN*BK)

// layout in dynamic LDS (elems): As0 | As1 | Bs0 | Bs1
#define AS(buf) (lds + (buf) * ABUF)
#define BS(buf) (lds + 2 * ABUF + (buf) * BBUF)

__global__ __launch_bounds__(512, 2) void gemm_qkv(
    const __hip_bfloat16* __restrict__ Xb,       // [20480][768]
    const __hip_bfloat16* __restrict__ WT,       // [2304][768]
    __hip_bfloat16* __restrict__ qb,
    __hip_bfloat16* __restrict__ kb,
    __hip_bfloat16* __restrict__ vt)
{
  extern __shared__ __hip_bfloat16 lds[];        // 131072 B
  const int tid = threadIdx.x;
  const int bm = blockIdx.x * BM;
  const int bn = blockIdx.y * BN;
  const int w = tid >> 6, lane = tid & 63;
  const int wr = w >> 2, wc = w & 3;             // 2M x 4N wave grid
  const int l16 = lane & 15, lq = lane >> 4;
  const int srow = lane >> 3;                    // 0..7 within chunk
  const int scol = ((lane & 7) ^ srow) * 8;      // pre-swizzled global col (elems)
  const int rsw  = (l16 & 7) * 8;                // read-side XOR (elems)
  const int chunk = w * 4;                       // first of 4 chunks per wave

  f32x4 acc[8][4];
  #pragma unroll
  for (int i = 0; i < 8; ++i)
    #pragma unroll
    for (int j = 0; j < 4; ++j) acc[i][j] = (f32x4){0.f,0.f,0.f,0.f};

  auto stage = [&](int buf, int k0){             // 8 gload_lds per wave
    #pragma unroll
    for (int it = 0; it < 4; ++it){
      int c = chunk + it;                        // 0..31, 8 rows per 1KB chunk
      int row = c * 8 + srow;
      gload16(&Xb[(size_t)(bm + row) * CC + k0 + scol], AS(buf) + c * 512);
      gload16(&WT[(size_t)(bn + row) * CC + k0 + scol], BS(buf) + c * 512);
    }
  };

  stage(0, 0);                                   // 8 outstanding
  int cur = 0;
  #pragma unroll
  for (int t = 0; t < NT; ++t){
    if (t + 1 < NT){
      stage(cur ^ 1, (t + 1) * BK);              // +8 -> up to 16 outstanding
      __builtin_amdgcn_sched_barrier(0);
      asm volatile("s_waitcnt vmcnt(8)" ::: "memory");   // oldest 8 (tile t) landed
    } else {
      asm volatile("s_waitcnt vmcnt(0)" ::: "memory");   // final tile landed
    }
    __builtin_amdgcn_s_barrier();                // all waves: tile t ready
    #pragma unroll
    for (int kc = 0; kc < 2; ++kc){
      const int acol = (kc*32 + lq*8) ^ rsw;
      short8 af[8], bfr[4];
      #pragma unroll
      for (int mi = 0; mi < 8; ++mi)
        af[mi] = *reinterpret_cast<const short8*>(AS(cur) + (wr*128 + mi*16 + l16) * BK + acol);
      #pragma unroll
      for (int ni = 0; ni < 4; ++ni)
        bfr[ni] = *reinterpret_cast<const short8*>(BS(cur) + (wc*64 + ni*16 + l16) * BK + acol);
      #pragma unroll
      for (int mi = 0; mi < 8; ++mi)
        #pragma unroll
        for (int ni = 0; ni < 4; ++ni)
          acc[mi][ni] = MFMA16(asbf(af[mi]), asbf(bfr[ni]), acc[mi][ni]);
    }
    __builtin_amdgcn_s_barrier();                // cur fully consumed before overwrite
    cur ^= 1;
  }

  // epilogue: scatter bf16 to q / k / vT
  #pragma unroll
  for (int mi = 0; mi < 8; ++mi){
    #pragma unroll
    for (int ni = 0; ni < 4; ++ni){
      #pragma unroll
      for (int r = 0; r < 4; ++r){
        int row = bm + wr*128 + mi*16 + lq*4 + r;  // token index in [0,20480)
        int col = bn + wc*64 + ni*16 + l16;        // qkv col in [0,2304)
        float val = acc[mi][ni][r];
        int b = row / NN, n = row % NN;
        int s = col / CC, rem = col % CC;
        int h = rem >> 6, dh = rem & 63;
        int bh = b * HH + h;
        __hip_bfloat16 bv = __float2bfloat16(val);
        if (s == 0)      qb[((size_t)bh * NN + n) * DH + dh] = bv;
        else if (s == 1) kb[((size_t)bh * NN + n) * DH + dh] = bv;
        else             vt[((size_t)bh * DH + dh) * NN + n] = bv;
      }
    }
  }
}

// ------------------------------------------------------------------
// Kernel 2: attention. One block = (b,h) x 64 query rows; 4 waves x 16 rows.
// NKT = number of 16-key tiles: 4 (mt part) or 20 (s part).
// ------------------------------------------------------------------
template<int NKT>
__global__ __launch_bounds__(256) void attn_kernel(
    const __hip_bfloat16* __restrict__ qb,
    const __hip_bfloat16* __restrict__ kb,
    const __hip_bfloat16* __restrict__ vt,
    __hip_bfloat16* __restrict__ ob)
{
  constexpr int KV   = NKT * 16;
  constexpr int PSTR = KV + 8;           // pad -> 2-way bank alias (free)
  __shared__ __hip_bfloat16 P[4][16][PSTR];

  const int tid = threadIdx.x;
  const int w = tid >> 6, lane = tid & 63;
  const int l16 = lane & 15, lq = lane >> 4;

  int bh, qbase;
  if (NKT == 4){ bh = blockIdx.x;      qbase = 0; }
  else         { bh = blockIdx.x >> 2; qbase = 64 + (blockIdx.x & 3) * 64; }
  const int qrow0 = qbase + w * 16;

  const __hip_bfloat16* qp = qb + ((size_t)bh * NN + qrow0) * DH;
  const __hip_bfloat16* kp = kb + (size_t)bh * NN * DH;
  const __hip_bfloat16* vp = vt + (size_t)bh * DH * NN;

  // Q fragments (held for whole kernel)
  short8 aq[2];
  #pragma unroll
  for (int kc = 0; kc < 2; ++kc)
    aq[kc] = *reinterpret_cast<const short8*>(&qp[l16 * DH + kc*32 + lq*8]);

  // S = Q K^T : s[kt][r] = S[lq*4+r][kt*16+l16]
  f32x4 s[NKT];
  #pragma unroll
  for (int kt = 0; kt < NKT; ++kt){
    f32x4 a = (f32x4){0.f,0.f,0.f,0.f};
    #pragma unroll
    for (int kc = 0; kc < 2; ++kc){
      short8 bk = *reinterpret_cast<const short8*>(&kp[(kt*16 + l16) * DH + kc*32 + lq*8]);
      a = MFMA16(asbf(aq[kc]), asbf(bk), a);
    }
    s[kt] = a;
  }

  // softmax over KV cols (rows lq*4+r); logits = s * 0.125
  const float scale = 0.125f;
  float sum[4];
  #pragma unroll
  for (int r = 0; r < 4; ++r){
    float mx = -1e30f;
    #pragma unroll
    for (int kt = 0; kt < NKT; ++kt) mx = fmaxf(mx, s[kt][r]);
    #pragma unroll
    for (int off = 1; off < 16; off <<= 1) mx = fmaxf(mx, __shfl_xor(mx, off));
    float sm = 0.f;
    #pragma unroll
    for (int kt = 0; kt < NKT; ++kt){
      float p = __expf((s[kt][r] - mx) * scale);
      __hip_bfloat16 pb = __float2bfloat16(p);
      P[w][lq*4 + r][kt*16 + l16] = pb;
      sm += __bfloat162float(pb);       // denominator consistent with bf16 P
    }
    #pragma unroll
    for (int off = 1; off < 16; off <<= 1) sm += __shfl_xor(sm, off);
    sum[r] = sm;
  }
  __syncthreads();   // drain LDS writes before cross-lane fragment reads

  // O = P V : per dh-tile nt, o[nt][r] = O[lq*4+r][nt*16+l16]
  f32x4 o[4];
  #pragma unroll
  for (int nt = 0; nt < 4; ++nt) o[nt] = (f32x4){0.f,0.f,0.f,0.f};
  #pragma unroll
  for (int kc = 0; kc < KV/32; ++kc){
    short8 ap = *reinterpret_cast<const short8*>(&P[w][l16][kc*32 + lq*8]);
    #pragma unroll
    for (int nt = 0; nt < 4; ++nt){
      short8 bv = *reinterpret_cast<const short8*>(&vp[(nt*16 + l16) * NN + kc*32 + lq*8]);
      o[nt] = MFMA16(asbf(ap), asbf(bv), o[nt]);
    }
  }

  // write o / sum -> ob[b*320 + qrow][h*64 + dh]
  const int b = bh / HH, h = bh % HH;
  #pragma unroll
  for (int nt = 0; nt < 4; ++nt){
    #pragma unroll
    for (int r = 0; r < 4; ++r){
      int qrow = qrow0 + lq*4 + r;
      int dh = nt*16 + l16;
      float val = o[nt][r] / sum[r];
      ob[((size_t)b * NN + qrow) * CC + h * DH + dh] = __float2bfloat16(val);
    }
  }
}

// ------------------------------------------------------------------
// Kernel 3: proj GEMM (M=20480, K=768, N=768) + bias, fp32 out.
// Same 256x256 counted-vmcnt structure as gemm_qkv.
// ------------------------------------------------------------------
__global__ __launch_bounds__(512, 2) void gemm_proj(
    const __hip_bfloat16* __restrict__ A,        // [20480][768] bf16
    const __hip_bfloat16* __restrict__ WT,       // [768][768] bf16 (transposed)
    const float* __restrict__ bias,
    float* __restrict__ out)
{
  extern __shared__ __hip_bfloat16 lds[];
  const int tid = threadIdx.x;
  const int bm = blockIdx.x * BM;
  const int bn = blockIdx.y * BN;
  const int w = tid >> 6, lane = tid & 63;
  const int wr = w >> 2, wc = w & 3;
  const int l16 = lane & 15, lq = lane >> 4;
  const int srow = lane >> 3;
  const int scol = ((lane & 7) ^ srow) * 8;
  const int rsw  = (l16 & 7) * 8;
  const int chunk = w * 4;

  f32x4 acc[8][4];
  #pragma unroll
  for (int i = 0; i < 8; ++i)
    #pragma unroll
    for (int j = 0; j < 4; ++j) acc[i][j] = (f32x4){0.f,0.f,0.f,0.f};

  auto stage = [&](int buf, int k0){
    #pragma unroll
    for (int it = 0; it < 4; ++it){
      int c = chunk + it;
      int row = c * 8 + srow;
      gload16(&A [(size_t)(bm + row) * CC + k0 + scol], AS(buf) + c * 512);
      gload16(&WT[(size_t)(bn + row) * CC + k0 + scol], BS(buf) + c * 512);
    }
  };

  stage(0, 0);
  int cur = 0;
  #pragma unroll
  for (int t = 0; t < NT; ++t){
    if (t + 1 < NT){
      stage(cur ^ 1, (t + 1) * BK);
      __builtin_amdgcn_sched_barrier(0);
      asm volatile("s_waitcnt vmcnt(8)" ::: "memory");
    } else {
      asm volatile("s_waitcnt vmcnt(0)" ::: "memory");
    }
    __builtin_amdgcn_s_barrier();
    #pragma unroll
    for (int kc = 0; kc < 2; ++kc){
      const int acol = (kc*32 + lq*8) ^ rsw;
      short8 af[8], bfr[4];
      #pragma unroll
      for (int mi = 0; mi < 8; ++mi)
        af[mi] = *reinterpret_cast<const short8*>(AS(cur) + (wr*128 + mi*16 + l16) * BK + acol);
      #pragma unroll
      for (int ni = 0; ni < 4; ++ni)
        bfr[ni] = *reinterpret_cast<const short8*>(BS(cur) + (wc*64 + ni*16 + l16) * BK + acol);
      #pragma unroll
      for (int mi = 0; mi < 8; ++mi)
        #pragma unroll
        for (int ni = 0; ni < 4; ++ni)
          acc[mi][ni] = MFMA16(asbf(af[mi]), asbf(bfr[ni]), acc[mi][ni]);
    }
    __builtin_amdgcn_s_barrier();
    cur ^= 1;
  }

  #pragma unroll
  for (int mi = 0; mi < 8; ++mi){
    #pragma unroll
    for (int ni = 0; ni < 4; ++ni){
      #pragma unroll
      for (int r = 0; r < 4; ++r){
        int row = bm + wr*128 + mi*16 + lq*4 + r;
        int col = bn + wc*64 + ni*16 + l16;
        out[(size_t)row * CC + col] = acc[mi][ni][r] + bias[col];
      }
    }
  }
}

// ------------------------------------------------------------------
extern "C" void kernel_launch(void* const* d_in, const int* in_sizes, int n_in,
                              void* d_out, int out_size, void* d_ws, size_t ws_size,
                              hipStream_t stream)
{
  const float* x     = (const float*)d_in[0];
  const float* Wqkv  = (const float*)d_in[1];
  const float* Wproj = (const float*)d_in[2];
  const float* bproj = (const float*)d_in[3];
  float* out = (float*)d_out;

  char* ws = (char*)d_ws;
  __hip_bfloat16* wqkvT  = (__hip_bfloat16*)ws; ws += (size_t)NC3 * CC * 2;      // 3.54 MB
  __hip_bfloat16* wprojT = (__hip_bfloat16*)ws; ws += (size_t)CC * CC * 2;       // 1.18 MB
  __hip_bfloat16* xb     = (__hip_bfloat16*)ws; ws += (size_t)MROWS * CC * 2;    // 31.46 MB
  const size_t headsz = (size_t)BB * HH * NN * DH * 2;                           // 31.46 MB
  __hip_bfloat16* qb = (__hip_bfloat16*)ws; ws += headsz;
  __hip_bfloat16* kb = (__hip_bfloat16*)ws; ws += headsz;
  __hip_bfloat16* vt = (__hip_bfloat16*)ws; ws += headsz;
  __hip_bfloat16* ob = (__hip_bfloat16*)ws; ws += headsz;

  const size_t ldsbytes = 2 * (ABUF + BBUF) * sizeof(__hip_bfloat16);  // 131072

  // 0) weights + x -> bf16
  convert_wT<<<dim3(NC3/64, CC/64), 256, 0, stream>>>(Wqkv, wqkvT, CC, NC3);
  convert_wT<<<dim3(CC/64,  CC/64), 256, 0, stream>>>(Wproj, wprojT, CC, CC);
  convert_x<<<MROWS * CC / (256*8), 256, 0, stream>>>(x, xb);
  // 1) qkv GEMM + scatter
  gemm_qkv<<<dim3(MROWS / BM, NC3 / BN), 512, ldsbytes, stream>>>(xb, wqkvT, qb, kb, vt);
  // 2) attention: mt (q 0..63, kv 64) and s (q 64..319, kv 320)
  attn_kernel<4><<<BB * HH, 256, 0, stream>>>(qb, kb, vt, ob);
  attn_kernel<20><<<BB * HH * 4, 256, 0, stream>>>(qb, kb, vt, ob);
  // 3) proj GEMM + bias
  gemm_proj<<<dim3(MROWS / BM, CC / BN), 512, ldsbytes, stream>>>(ob, wprojT, bproj, out);
}

// Round 7
// 299.590 us; speedup vs baseline: 1.0372x; 1.0372x over previous
//
#include <hip/hip_runtime.h>
#include <hip/hip_bf16.h>
#include <stdint.h>

// ---- problem constants ----
#define BB 64
#define NN 320
#define CC 768
#define HH 12
#define DH 64
#define NC3 2304
#define MROWS (BB*NN)   // 20480

typedef __attribute__((ext_vector_type(8))) short short8;
typedef __attribute__((ext_vector_type(4))) float f32x4;
typedef __attribute__((ext_vector_type(8))) __bf16 bf16x8;

union BF8U { short8 s; bf16x8 b; };
static __device__ __forceinline__ bf16x8 asbf(short8 v){ BF8U u; u.s = v; return u.b; }

#define MFMA16(a,b,c) __builtin_amdgcn_mfma_f32_16x16x32_bf16((a),(b),(c),0,0,0)

// async global->LDS, 16B per lane; LDS dest = wave-uniform base + lane*16
static __device__ __forceinline__ void gload16(const void* g, void* l){
  __builtin_amdgcn_global_load_lds(
      (const __attribute__((address_space(1))) void*)g,
      (__attribute__((address_space(3))) void*)l, 16, 0, 0);
}

// ------------------------------------------------------------------
// Kernel 0a: tiled transpose+convert  outT[n][k] = bf16(in[k][n])
// ------------------------------------------------------------------
__global__ __launch_bounds__(256) void convert_wT(
    const float* __restrict__ in, __hip_bfloat16* __restrict__ outT,
    int K, int Nc)
{
  __shared__ __hip_bfloat16 t[64][72];   // +8 pad
  const int n0 = blockIdx.x * 64, k0 = blockIdx.y * 64;
  const int tid = threadIdx.x;
  const int tx = tid & 15, ty = tid >> 4;          // 16 x 16

  #pragma unroll
  for (int i = 0; i < 4; ++i){
    int kl = ty + i * 16;
    float4 v = *reinterpret_cast<const float4*>(&in[(size_t)(k0 + kl) * Nc + n0 + tx * 4]);
    t[tx*4+0][kl] = __float2bfloat16(v.x);
    t[tx*4+1][kl] = __float2bfloat16(v.y);
    t[tx*4+2][kl] = __float2bfloat16(v.z);
    t[tx*4+3][kl] = __float2bfloat16(v.w);
  }
  __syncthreads();
  #pragma unroll
  for (int j = 0; j < 2; ++j){
    int nl = (tid >> 3) + j * 32;
    int kl = (tid & 7) * 8;
    short8 v = *reinterpret_cast<const short8*>(&t[nl][kl]);
    *reinterpret_cast<short8*>(&outT[(size_t)(n0 + nl) * K + k0 + kl]) = v;
  }
}

// ------------------------------------------------------------------
// Kernel 0b: convert x fp32 -> bf16 (row-major, same layout)
// ------------------------------------------------------------------
__global__ __launch_bounds__(256) void convert_x(
    const float* __restrict__ X, __hip_bfloat16* __restrict__ Xb)
{
  size_t i = ((size_t)blockIdx.x * 256 + threadIdx.x) * 8;
  float4 a = *reinterpret_cast<const float4*>(&X[i]);
  float4 b = *reinterpret_cast<const float4*>(&X[i + 4]);
  __hip_bfloat16 t[8] = {__float2bfloat16(a.x), __float2bfloat16(a.y),
                         __float2bfloat16(a.z), __float2bfloat16(a.w),
                         __float2bfloat16(b.x), __float2bfloat16(b.y),
                         __float2bfloat16(b.z), __float2bfloat16(b.w)};
  *reinterpret_cast<short8*>(&Xb[i]) = *reinterpret_cast<const short8*>(t);
}

// ------------------------------------------------------------------
// GEMM: 128x128 tile, BK=64, 4 waves (2x2), single-buffered 32KB LDS,
// m97 structure. XOR-swizzle both-sides (rule #21), gload_lds width=16.
// KEY CHANGE (r7): __launch_bounds__(256, 4) forces VGPR+AGPR <= 128
// (gfx950 unified file; occupancy halves at 128 regs, m69) -> 4 waves/
// SIMD, 4 blocks/CU co-resident. All prior rounds sat at 2 waves/SIMD
// (21% occupancy) because acc AGPRs pushed totals past 128; cross-wave
// overlap (m114) is what actually hides stage+LDS latency.
// Inner loop holds bfr[4] + 1 af (20 operand VGPRs) to help the cap.
// ------------------------------------------------------------------
#define BM 128
#define BN 128
#define BK 64
#define NT (CC/BK)   // 12

__global__ __launch_bounds__(256, 4) void gemm_qkv(
    const __hip_bfloat16* __restrict__ Xb,       // [20480][768]
    const __hip_bfloat16* __restrict__ WT,       // [2304][768]
    __hip_bfloat16* __restrict__ qb,
    __hip_bfloat16* __restrict__ kb,
    __hip_bfloat16* __restrict__ vt)
{
  __shared__ __hip_bfloat16 As[BM][BK];   // 16 KB, linear (gload_lds dest)
  __shared__ __hip_bfloat16 Bs[BN][BK];   // 16 KB
  const int tid = threadIdx.x;
  const int bm = blockIdx.x * BM;
  const int bn = blockIdx.y * BN;
  const int w = tid >> 6, lane = tid & 63;
  const int wr = w >> 1, wc = w & 1;
  const int l16 = lane & 15, lq = lane >> 4;
  const int srow = lane >> 3;                          // 0..7 within chunk
  const int scol = ((lane & 7) ^ srow) * 8;            // pre-swizzled global col (elems)
  const int rsw  = (l16 & 7) * 8;                      // read-side XOR (elems)

  f32x4 acc[4][4];
  #pragma unroll
  for (int i = 0; i < 4; ++i)
    #pragma unroll
    for (int j = 0; j < 4; ++j) acc[i][j] = (f32x4){0.f,0.f,0.f,0.f};

  for (int k0 = 0; k0 < CC; k0 += BK){
    // stage A+B via async global->LDS (4 chunks each per wave)
    #pragma unroll
    for (int it = 0; it < 4; ++it){
      int c = w * 4 + it;                 // 0..15, 8 rows per 1KB chunk
      int row = c * 8 + srow;
      gload16(&Xb[(size_t)(bm + row) * CC + k0 + scol], &As[0][0] + c * 512);
      gload16(&WT[(size_t)(bn + row) * CC + k0 + scol], &Bs[0][0] + c * 512);
    }
    __syncthreads();   // vmcnt(0) drain + barrier: tile ready
    #pragma unroll
    for (int kc = 0; kc < 2; ++kc){
      const int acol = (kc*32 + lq*8) ^ rsw;
      short8 bfr[4];
      #pragma unroll
      for (int ni = 0; ni < 4; ++ni)
        bfr[ni] = *reinterpret_cast<const short8*>(&Bs[wc*64 + ni*16 + l16][acol]);
      #pragma unroll
      for (int mi = 0; mi < 4; ++mi){
        short8 af = *reinterpret_cast<const short8*>(&As[wr*64 + mi*16 + l16][acol]);
        #pragma unroll
        for (int ni = 0; ni < 4; ++ni)
          acc[mi][ni] = MFMA16(asbf(af), asbf(bfr[ni]), acc[mi][ni]);
      }
    }
    __syncthreads();   // compute done before next stage overwrites
  }

  // epilogue: scatter bf16 to q / k / vT
  #pragma unroll
  for (int mi = 0; mi < 4; ++mi){
    #pragma unroll
    for (int ni = 0; ni < 4; ++ni){
      #pragma unroll
      for (int r = 0; r < 4; ++r){
        int row = bm + wr*64 + mi*16 + lq*4 + r;   // token index in [0,20480)
        int col = bn + wc*64 + ni*16 + l16;        // qkv col in [0,2304)
        float val = acc[mi][ni][r];
        int b = row / NN, n = row % NN;
        int s = col / CC, rem = col % CC;
        int h = rem >> 6, dh = rem & 63;
        int bh = b * HH + h;
        __hip_bfloat16 bv = __float2bfloat16(val);
        if (s == 0)      qb[((size_t)bh * NN + n) * DH + dh] = bv;
        else if (s == 1) kb[((size_t)bh * NN + n) * DH + dh] = bv;
        else             vt[((size_t)bh * DH + dh) * NN + n] = bv;
      }
    }
  }
}

// ------------------------------------------------------------------
// Kernel 2: attention. One block = (b,h) x 64 query rows; 4 waves x 16 rows.
// NKT = number of 16-key tiles: 4 (mt part) or 20 (s part).
// ------------------------------------------------------------------
template<int NKT>
__global__ __launch_bounds__(256) void attn_kernel(
    const __hip_bfloat16* __restrict__ qb,
    const __hip_bfloat16* __restrict__ kb,
    const __hip_bfloat16* __restrict__ vt,
    __hip_bfloat16* __restrict__ ob)
{
  constexpr int KV   = NKT * 16;
  constexpr int PSTR = KV + 8;           // pad -> 2-way bank alias (free)
  __shared__ __hip_bfloat16 P[4][16][PSTR];

  const int tid = threadIdx.x;
  const int w = tid >> 6, lane = tid & 63;
  const int l16 = lane & 15, lq = lane >> 4;

  int bh, qbase;
  if (NKT == 4){ bh = blockIdx.x;      qbase = 0; }
  else         { bh = blockIdx.x >> 2; qbase = 64 + (blockIdx.x & 3) * 64; }
  const int qrow0 = qbase + w * 16;

  const __hip_bfloat16* qp = qb + ((size_t)bh * NN + qrow0) * DH;
  const __hip_bfloat16* kp = kb + (size_t)bh * NN * DH;
  const __hip_bfloat16* vp = vt + (size_t)bh * DH * NN;

  // Q fragments (held for whole kernel)
  short8 aq[2];
  #pragma unroll
  for (int kc = 0; kc < 2; ++kc)
    aq[kc] = *reinterpret_cast<const short8*>(&qp[l16 * DH + kc*32 + lq*8]);

  // S = Q K^T : s[kt][r] = S[lq*4+r][kt*16+l16]
  f32x4 s[NKT];
  #pragma unroll
  for (int kt = 0; kt < NKT; ++kt){
    f32x4 a = (f32x4){0.f,0.f,0.f,0.f};
    #pragma unroll
    for (int kc = 0; kc < 2; ++kc){
      short8 bk = *reinterpret_cast<const short8*>(&kp[(kt*16 + l16) * DH + kc*32 + lq*8]);
      a = MFMA16(asbf(aq[kc]), asbf(bk), a);
    }
    s[kt] = a;
  }

  // softmax over KV cols (rows lq*4+r); logits = s * 0.125
  const float scale = 0.125f;
  float sum[4];
  #pragma unroll
  for (int r = 0; r < 4; ++r){
    float mx = -1e30f;
    #pragma unroll
    for (int kt = 0; kt < NKT; ++kt) mx = fmaxf(mx, s[kt][r]);
    #pragma unroll
    for (int off = 1; off < 16; off <<= 1) mx = fmaxf(mx, __shfl_xor(mx, off));
    float sm = 0.f;
    #pragma unroll
    for (int kt = 0; kt < NKT; ++kt){
      float p = __expf((s[kt][r] - mx) * scale);
      __hip_bfloat16 pb = __float2bfloat16(p);
      P[w][lq*4 + r][kt*16 + l16] = pb;
      sm += __bfloat162float(pb);       // denominator consistent with bf16 P
    }
    #pragma unroll
    for (int off = 1; off < 16; off <<= 1) sm += __shfl_xor(sm, off);
    sum[r] = sm;
  }
  __syncthreads();   // drain LDS writes before cross-lane fragment reads

  // O = P V : per dh-tile nt, o[nt][r] = O[lq*4+r][nt*16+l16]
  f32x4 o[4];
  #pragma unroll
  for (int nt = 0; nt < 4; ++nt) o[nt] = (f32x4){0.f,0.f,0.f,0.f};
  #pragma unroll
  for (int kc = 0; kc < KV/32; ++kc){
    short8 ap = *reinterpret_cast<const short8*>(&P[w][l16][kc*32 + lq*8]);
    #pragma unroll
    for (int nt = 0; nt < 4; ++nt){
      short8 bv = *reinterpret_cast<const short8*>(&vp[(nt*16 + l16) * NN + kc*32 + lq*8]);
      o[nt] = MFMA16(asbf(ap), asbf(bv), o[nt]);
    }
  }

  // write o / sum -> ob[b*320 + qrow][h*64 + dh]
  const int b = bh / HH, h = bh % HH;
  #pragma unroll
  for (int nt = 0; nt < 4; ++nt){
    #pragma unroll
    for (int r = 0; r < 4; ++r){
      int qrow = qrow0 + lq*4 + r;
      int dh = nt*16 + l16;
      float val = o[nt][r] / sum[r];
      ob[((size_t)b * NN + qrow) * CC + h * DH + dh] = __float2bfloat16(val);
    }
  }
}

// ------------------------------------------------------------------
// Kernel 3: proj GEMM (M=20480, K=768, N=768) + bias, fp32 out.
// Same 128x128 single-buffered launch_bounds(256,4) structure.
// ------------------------------------------------------------------
__global__ __launch_bounds__(256, 4) void gemm_proj(
    const __hip_bfloat16* __restrict__ A,        // [20480][768] bf16
    const __hip_bfloat16* __restrict__ WT,       // [768][768] bf16 (transposed)
    const float* __restrict__ bias,
    float* __restrict__ out)
{
  __shared__ __hip_bfloat16 As[BM][BK];
  __shared__ __hip_bfloat16 Bs[BN][BK];
  const int tid = threadIdx.x;
  const int bm = blockIdx.x * BM;
  const int bn = blockIdx.y * BN;
  const int w = tid >> 6, lane = tid & 63;
  const int wr = w >> 1, wc = w & 1;
  const int l16 = lane & 15, lq = lane >> 4;
  const int srow = lane >> 3;
  const int scol = ((lane & 7) ^ srow) * 8;
  const int rsw  = (l16 & 7) * 8;

  f32x4 acc[4][4];
  #pragma unroll
  for (int i = 0; i < 4; ++i)
    #pragma unroll
    for (int j = 0; j < 4; ++j) acc[i][j] = (f32x4){0.f,0.f,0.f,0.f};

  for (int k0 = 0; k0 < CC; k0 += BK){
    #pragma unroll
    for (int it = 0; it < 4; ++it){
      int c = w * 4 + it;
      int row = c * 8 + srow;
      gload16(&A [(size_t)(bm + row) * CC + k0 + scol], &As[0][0] + c * 512);
      gload16(&WT[(size_t)(bn + row) * CC + k0 + scol], &Bs[0][0] + c * 512);
    }
    __syncthreads();
    #pragma unroll
    for (int kc = 0; kc < 2; ++kc){
      const int acol = (kc*32 + lq*8) ^ rsw;
      short8 bfr[4];
      #pragma unroll
      for (int ni = 0; ni < 4; ++ni)
        bfr[ni] = *reinterpret_cast<const short8*>(&Bs[wc*64 + ni*16 + l16][acol]);
      #pragma unroll
      for (int mi = 0; mi < 4; ++mi){
        short8 af = *reinterpret_cast<const short8*>(&As[wr*64 + mi*16 + l16][acol]);
        #pragma unroll
        for (int ni = 0; ni < 4; ++ni)
          acc[mi][ni] = MFMA16(asbf(af), asbf(bfr[ni]), acc[mi][ni]);
      }
    }
    __syncthreads();
  }

  #pragma unroll
  for (int mi = 0; mi < 4; ++mi){
    #pragma unroll
    for (int ni = 0; ni < 4; ++ni){
      #pragma unroll
      for (int r = 0; r < 4; ++r){
        int row = bm + wr*64 + mi*16 + lq*4 + r;
        int col = bn + wc*64 + ni*16 + l16;
        out[(size_t)row * CC + col] = acc[mi][ni][r] + bias[col];
      }
    }
  }
}

// ------------------------------------------------------------------
extern "C" void kernel_launch(void* const* d_in, const int* in_sizes, int n_in,
                              void* d_out, int out_size, void* d_ws, size_t ws_size,
                              hipStream_t stream)
{
  const float* x     = (const float*)d_in[0];
  const float* Wqkv  = (const float*)d_in[1];
  const float* Wproj = (const float*)d_in[2];
  const float* bproj = (const float*)d_in[3];
  float* out = (float*)d_out;

  char* ws = (char*)d_ws;
  __hip_bfloat16* wqkvT  = (__hip_bfloat16*)ws; ws += (size_t)NC3 * CC * 2;      // 3.54 MB
  __hip_bfloat16* wprojT = (__hip_bfloat16*)ws; ws += (size_t)CC * CC * 2;       // 1.18 MB
  __hip_bfloat16* xb     = (__hip_bfloat16*)ws; ws += (size_t)MROWS * CC * 2;    // 31.46 MB
  const size_t headsz = (size_t)BB * HH * NN * DH * 2;                           // 31.46 MB
  __hip_bfloat16* qb = (__hip_bfloat16*)ws; ws += headsz;
  __hip_bfloat16* kb = (__hip_bfloat16*)ws; ws += headsz;
  __hip_bfloat16* vt = (__hip_bfloat16*)ws; ws += headsz;
  __hip_bfloat16* ob = (__hip_bfloat16*)ws; ws += headsz;

  // 0) weights + x -> bf16
  convert_wT<<<dim3(NC3/64, CC/64), 256, 0, stream>>>(Wqkv, wqkvT, CC, NC3);
  convert_wT<<<dim3(CC/64,  CC/64), 256, 0, stream>>>(Wproj, wprojT, CC, CC);
  convert_x<<<MROWS * CC / (256*8), 256, 0, stream>>>(x, xb);
  // 1) qkv GEMM + scatter
  gemm_qkv<<<dim3(MROWS / BM, NC3 / BN), 256, 0, stream>>>(xb, wqkvT, qb, kb, vt);
  // 2) attention: mt (q 0..63, kv 64) and s (q 64..319, kv 320)
  attn_kernel<4><<<BB * HH, 256, 0, stream>>>(qb, kb, vt, ob);
  attn_kernel<20><<<BB * HH * 4, 256, 0, stream>>>(qb, kb, vt, ob);
  // 3) proj GEMM + bias
  gemm_proj<<<dim3(MROWS / BM, CC / BN), 256, 0, stream>>>(ob, wprojT, bproj, out);
}

// Round 8
// 299.030 us; speedup vs baseline: 1.0392x; 1.0019x over previous
//
#include <hip/hip_runtime.h>
#include <hip/hip_bf16.h>
#include <stdint.h>

// ---- problem constants ----
#define BB 64
#define NN 320
#define CC 768
#define HH 12
#define DH 64
#define NC3 2304
#define MROWS (BB*NN)   // 20480

typedef __attribute__((ext_vector_type(8))) short short8;
typedef __attribute__((ext_vector_type(4))) float f32x4;
typedef __attribute__((ext_vector_type(8))) __bf16 bf16x8;

union BF8U { short8 s; bf16x8 b; };
static __device__ __forceinline__ bf16x8 asbf(short8 v){ BF8U u; u.s = v; return u.b; }

#define MFMA16(a,b,c) __builtin_amdgcn_mfma_f32_16x16x32_bf16((a),(b),(c),0,0,0)

// async global->LDS, 16B per lane; LDS dest = wave-uniform base + lane*16
static __device__ __forceinline__ void gload16(const void* g, void* l){
  __builtin_amdgcn_global_load_lds(
      (const __attribute__((address_space(1))) void*)g,
      (__attribute__((address_space(3))) void*)l, 16, 0, 0);
}

// ------------------------------------------------------------------
// Kernel 0a: tiled transpose+convert  outT[n][k] = bf16(in[k][n])
// ------------------------------------------------------------------
__global__ __launch_bounds__(256) void convert_wT(
    const float* __restrict__ in, __hip_bfloat16* __restrict__ outT,
    int K, int Nc)
{
  __shared__ __hip_bfloat16 t[64][72];   // +8 pad
  const int n0 = blockIdx.x * 64, k0 = blockIdx.y * 64;
  const int tid = threadIdx.x;
  const int tx = tid & 15, ty = tid >> 4;          // 16 x 16

  #pragma unroll
  for (int i = 0; i < 4; ++i){
    int kl = ty + i * 16;
    float4 v = *reinterpret_cast<const float4*>(&in[(size_t)(k0 + kl) * Nc + n0 + tx * 4]);
    t[tx*4+0][kl] = __float2bfloat16(v.x);
    t[tx*4+1][kl] = __float2bfloat16(v.y);
    t[tx*4+2][kl] = __float2bfloat16(v.z);
    t[tx*4+3][kl] = __float2bfloat16(v.w);
  }
  __syncthreads();
  #pragma unroll
  for (int j = 0; j < 2; ++j){
    int nl = (tid >> 3) + j * 32;
    int kl = (tid & 7) * 8;
    short8 v = *reinterpret_cast<const short8*>(&t[nl][kl]);
    *reinterpret_cast<short8*>(&outT[(size_t)(n0 + nl) * K + k0 + kl]) = v;
  }
}

// ------------------------------------------------------------------
// Kernel 0b: convert x fp32 -> bf16 (row-major, same layout)
// ------------------------------------------------------------------
__global__ __launch_bounds__(256) void convert_x(
    const float* __restrict__ X, __hip_bfloat16* __restrict__ Xb)
{
  size_t i = ((size_t)blockIdx.x * 256 + threadIdx.x) * 8;
  float4 a = *reinterpret_cast<const float4*>(&X[i]);
  float4 b = *reinterpret_cast<const float4*>(&X[i + 4]);
  __hip_bfloat16 t[8] = {__float2bfloat16(a.x), __float2bfloat16(a.y),
                         __float2bfloat16(a.z), __float2bfloat16(a.w),
                         __float2bfloat16(b.x), __float2bfloat16(b.y),
                         __float2bfloat16(b.z), __float2bfloat16(b.w)};
  *reinterpret_cast<short8*>(&Xb[i]) = *reinterpret_cast<const short8*>(t);
}

// ------------------------------------------------------------------
// GEMM: 128x128 tile, BK=64, 4 waves (2x2), single-buffered 32KB LDS,
// m97 structure. XOR-swizzle both-sides (rule #21), gload_lds width=16.
// KEY CHANGE (r7): __launch_bounds__(256, 4) forces VGPR+AGPR <= 128
// (gfx950 unified file; occupancy halves at 128 regs, m69) -> 4 waves/
// SIMD, 4 blocks/CU co-resident. All prior rounds sat at 2 waves/SIMD
// (21% occupancy) because acc AGPRs pushed totals past 128; cross-wave
// overlap (m114) is what actually hides stage+LDS latency.
// Inner loop holds bfr[4] + 1 af (20 operand VGPRs) to help the cap.
// ------------------------------------------------------------------
#define BM 128
#define BN 128
#define BK 64
#define NT (CC/BK)   // 12

__global__ __launch_bounds__(256, 4) void gemm_qkv(
    const __hip_bfloat16* __restrict__ Xb,       // [20480][768]
    const __hip_bfloat16* __restrict__ WT,       // [2304][768]
    __hip_bfloat16* __restrict__ qb,
    __hip_bfloat16* __restrict__ kb,
    __hip_bfloat16* __restrict__ vt)
{
  __shared__ __hip_bfloat16 As[BM][BK];   // 16 KB, linear (gload_lds dest)
  __shared__ __hip_bfloat16 Bs[BN][BK];   // 16 KB
  const int tid = threadIdx.x;
  const int bm = blockIdx.x * BM;
  const int bn = blockIdx.y * BN;
  const int w = tid >> 6, lane = tid & 63;
  const int wr = w >> 1, wc = w & 1;
  const int l16 = lane & 15, lq = lane >> 4;
  const int srow = lane >> 3;                          // 0..7 within chunk
  const int scol = ((lane & 7) ^ srow) * 8;            // pre-swizzled global col (elems)
  const int rsw  = (l16 & 7) * 8;                      // read-side XOR (elems)

  f32x4 acc[4][4];
  #pragma unroll
  for (int i = 0; i < 4; ++i)
    #pragma unroll
    for (int j = 0; j < 4; ++j) acc[i][j] = (f32x4){0.f,0.f,0.f,0.f};

  for (int k0 = 0; k0 < CC; k0 += BK){
    // stage A+B via async global->LDS (4 chunks each per wave)
    #pragma unroll
    for (int it = 0; it < 4; ++it){
      int c = w * 4 + it;                 // 0..15, 8 rows per 1KB chunk
      int row = c * 8 + srow;
      gload16(&Xb[(size_t)(bm + row) * CC + k0 + scol], &As[0][0] + c * 512);
      gload16(&WT[(size_t)(bn + row) * CC + k0 + scol], &Bs[0][0] + c * 512);
    }
    __syncthreads();   // vmcnt(0) drain + barrier: tile ready
    #pragma unroll
    for (int kc = 0; kc < 2; ++kc){
      const int acol = (kc*32 + lq*8) ^ rsw;
      short8 bfr[4];
      #pragma unroll
      for (int ni = 0; ni < 4; ++ni)
        bfr[ni] = *reinterpret_cast<const short8*>(&Bs[wc*64 + ni*16 + l16][acol]);
      #pragma unroll
      for (int mi = 0; mi < 4; ++mi){
        short8 af = *reinterpret_cast<const short8*>(&As[wr*64 + mi*16 + l16][acol]);
        #pragma unroll
        for (int ni = 0; ni < 4; ++ni)
          acc[mi][ni] = MFMA16(asbf(af), asbf(bfr[ni]), acc[mi][ni]);
      }
    }
    __syncthreads();   // compute done before next stage overwrites
  }

  // epilogue: scatter bf16 to q / k / vT
  #pragma unroll
  for (int mi = 0; mi < 4; ++mi){
    #pragma unroll
    for (int ni = 0; ni < 4; ++ni){
      #pragma unroll
      for (int r = 0; r < 4; ++r){
        int row = bm + wr*64 + mi*16 + lq*4 + r;   // token index in [0,20480)
        int col = bn + wc*64 + ni*16 + l16;        // qkv col in [0,2304)
        float val = acc[mi][ni][r];
        int b = row / NN, n = row % NN;
        int s = col / CC, rem = col % CC;
        int h = rem >> 6, dh = rem & 63;
        int bh = b * HH + h;
        __hip_bfloat16 bv = __float2bfloat16(val);
        if (s == 0)      qb[((size_t)bh * NN + n) * DH + dh] = bv;
        else if (s == 1) kb[((size_t)bh * NN + n) * DH + dh] = bv;
        else             vt[((size_t)bh * DH + dh) * NN + n] = bv;
      }
    }
  }
}

// ------------------------------------------------------------------
// Kernel 2: attention. One block = (b,h) x 64 query rows; 4 waves x 16 rows.
// NKT = number of 16-key tiles: 4 (mt part) or 20 (s part).
// ------------------------------------------------------------------
template<int NKT>
__global__ __launch_bounds__(256) void attn_kernel(
    const __hip_bfloat16* __restrict__ qb,
    const __hip_bfloat16* __restrict__ kb,
    const __hip_bfloat16* __restrict__ vt,
    __hip_bfloat16* __restrict__ ob)
{
  constexpr int KV   = NKT * 16;
  constexpr int PSTR = KV + 8;           // pad -> 2-way bank alias (free)
  __shared__ __hip_bfloat16 P[4][16][PSTR];

  const int tid = threadIdx.x;
  const int w = tid >> 6, lane = tid & 63;
  const int l16 = lane & 15, lq = lane >> 4;

  int bh, qbase;
  if (NKT == 4){ bh = blockIdx.x;      qbase = 0; }
  else         { bh = blockIdx.x >> 2; qbase = 64 + (blockIdx.x & 3) * 64; }
  const int qrow0 = qbase + w * 16;

  const __hip_bfloat16* qp = qb + ((size_t)bh * NN + qrow0) * DH;
  const __hip_bfloat16* kp = kb + (size_t)bh * NN * DH;
  const __hip_bfloat16* vp = vt + (size_t)bh * DH * NN;

  // Q fragments (held for whole kernel)
  short8 aq[2];
  #pragma unroll
  for (int kc = 0; kc < 2; ++kc)
    aq[kc] = *reinterpret_cast<const short8*>(&qp[l16 * DH + kc*32 + lq*8]);

  // S = Q K^T : s[kt][r] = S[lq*4+r][kt*16+l16]
  f32x4 s[NKT];
  #pragma unroll
  for (int kt = 0; kt < NKT; ++kt){
    f32x4 a = (f32x4){0.f,0.f,0.f,0.f};
    #pragma unroll
    for (int kc = 0; kc < 2; ++kc){
      short8 bk = *reinterpret_cast<const short8*>(&kp[(kt*16 + l16) * DH + kc*32 + lq*8]);
      a = MFMA16(asbf(aq[kc]), asbf(bk), a);
    }
    s[kt] = a;
  }

  // softmax over KV cols (rows lq*4+r); logits = s * 0.125
  const float scale = 0.125f;
  float sum[4];
  #pragma unroll
  for (int r = 0; r < 4; ++r){
    float mx = -1e30f;
    #pragma unroll
    for (int kt = 0; kt < NKT; ++kt) mx = fmaxf(mx, s[kt][r]);
    #pragma unroll
    for (int off = 1; off < 16; off <<= 1) mx = fmaxf(mx, __shfl_xor(mx, off));
    float sm = 0.f;
    #pragma unroll
    for (int kt = 0; kt < NKT; ++kt){
      float p = __expf((s[kt][r] - mx) * scale);
      __hip_bfloat16 pb = __float2bfloat16(p);
      P[w][lq*4 + r][kt*16 + l16] = pb;
      sm += __bfloat162float(pb);       // denominator consistent with bf16 P
    }
    #pragma unroll
    for (int off = 1; off < 16; off <<= 1) sm += __shfl_xor(sm, off);
    sum[r] = sm;
  }
  __syncthreads();   // drain LDS writes before cross-lane fragment reads

  // O = P V : per dh-tile nt, o[nt][r] = O[lq*4+r][nt*16+l16]
  f32x4 o[4];
  #pragma unroll
  for (int nt = 0; nt < 4; ++nt) o[nt] = (f32x4){0.f,0.f,0.f,0.f};
  #pragma unroll
  for (int kc = 0; kc < KV/32; ++kc){
    short8 ap = *reinterpret_cast<const short8*>(&P[w][l16][kc*32 + lq*8]);
    #pragma unroll
    for (int nt = 0; nt < 4; ++nt){
      short8 bv = *reinterpret_cast<const short8*>(&vp[(nt*16 + l16) * NN + kc*32 + lq*8]);
      o[nt] = MFMA16(asbf(ap), asbf(bv), o[nt]);
    }
  }

  // write o / sum -> ob[b*320 + qrow][h*64 + dh]
  const int b = bh / HH, h = bh % HH;
  #pragma unroll
  for (int nt = 0; nt < 4; ++nt){
    #pragma unroll
    for (int r = 0; r < 4; ++r){
      int qrow = qrow0 + lq*4 + r;
      int dh = nt*16 + l16;
      float val = o[nt][r] / sum[r];
      ob[((size_t)b * NN + qrow) * CC + h * DH + dh] = __float2bfloat16(val);
    }
  }
}

// ------------------------------------------------------------------
// Kernel 3: proj GEMM (M=20480, K=768, N=768) + bias, fp32 out.
// Same 128x128 single-buffered launch_bounds(256,4) structure.
// ------------------------------------------------------------------
__global__ __launch_bounds__(256, 4) void gemm_proj(
    const __hip_bfloat16* __restrict__ A,        // [20480][768] bf16
    const __hip_bfloat16* __restrict__ WT,       // [768][768] bf16 (transposed)
    const float* __restrict__ bias,
    float* __restrict__ out)
{
  __shared__ __hip_bfloat16 As[BM][BK];
  __shared__ __hip_bfloat16 Bs[BN][BK];
  const int tid = threadIdx.x;
  const int bm = blockIdx.x * BM;
  const int bn = blockIdx.y * BN;
  const int w = tid >> 6, lane = tid & 63;
  const int wr = w >> 1, wc = w & 1;
  const int l16 = lane & 15, lq = lane >> 4;
  const int srow = lane >> 3;
  const int scol = ((lane & 7) ^ srow) * 8;
  const int rsw  = (l16 & 7) * 8;

  f32x4 acc[4][4];
  #pragma unroll
  for (int i = 0; i < 4; ++i)
    #pragma unroll
    for (int j = 0; j < 4; ++j) acc[i][j] = (f32x4){0.f,0.f,0.f,0.f};

  for (int k0 = 0; k0 < CC; k0 += BK){
    #pragma unroll
    for (int it = 0; it < 4; ++it){
      int c = w * 4 + it;
      int row = c * 8 + srow;
      gload16(&A [(size_t)(bm + row) * CC + k0 + scol], &As[0][0] + c * 512);
      gload16(&WT[(size_t)(bn + row) * CC + k0 + scol], &Bs[0][0] + c * 512);
    }
    __syncthreads();
    #pragma unroll
    for (int kc = 0; kc < 2; ++kc){
      const int acol = (kc*32 + lq*8) ^ rsw;
      short8 bfr[4];
      #pragma unroll
      for (int ni = 0; ni < 4; ++ni)
        bfr[ni] = *reinterpret_cast<const short8*>(&Bs[wc*64 + ni*16 + l16][acol]);
      #pragma unroll
      for (int mi = 0; mi < 4; ++mi){
        short8 af = *reinterpret_cast<const short8*>(&As[wr*64 + mi*16 + l16][acol]);
        #pragma unroll
        for (int ni = 0; ni < 4; ++ni)
          acc[mi][ni] = MFMA16(asbf(af), asbf(bfr[ni]), acc[mi][ni]);
      }
    }
    __syncthreads();
  }

  #pragma unroll
  for (int mi = 0; mi < 4; ++mi){
    #pragma unroll
    for (int ni = 0; ni < 4; ++ni){
      #pragma unroll
      for (int r = 0; r < 4; ++r){
        int row = bm + wr*64 + mi*16 + lq*4 + r;
        int col = bn + wc*64 + ni*16 + l16;
        out[(size_t)row * CC + col] = acc[mi][ni][r] + bias[col];
      }
    }
  }
}

// ------------------------------------------------------------------
extern "C" void kernel_launch(void* const* d_in, const int* in_sizes, int n_in,
                              void* d_out, int out_size, void* d_ws, size_t ws_size,
                              hipStream_t stream)
{
  const float* x     = (const float*)d_in[0];
  const float* Wqkv  = (const float*)d_in[1];
  const float* Wproj = (const float*)d_in[2];
  const float* bproj = (const float*)d_in[3];
  float* out = (float*)d_out;

  char* ws = (char*)d_ws;
  __hip_bfloat16* wqkvT  = (__hip_bfloat16*)ws; ws += (size_t)NC3 * CC * 2;      // 3.54 MB
  __hip_bfloat16* wprojT = (__hip_bfloat16*)ws; ws += (size_t)CC * CC * 2;       // 1.18 MB
  __hip_bfloat16* xb     = (__hip_bfloat16*)ws; ws += (size_t)MROWS * CC * 2;    // 31.46 MB
  const size_t headsz = (size_t)BB * HH * NN * DH * 2;                           // 31.46 MB
  __hip_bfloat16* qb = (__hip_bfloat16*)ws; ws += headsz;
  __hip_bfloat16* kb = (__hip_bfloat16*)ws; ws += headsz;
  __hip_bfloat16* vt = (__hip_bfloat16*)ws; ws += headsz;
  __hip_bfloat16* ob = (__hip_bfloat16*)ws; ws += headsz;

  // 0) weights + x -> bf16
  convert_wT<<<dim3(NC3/64, CC/64), 256, 0, stream>>>(Wqkv, wqkvT, CC, NC3);
  convert_wT<<<dim3(CC/64,  CC/64), 256, 0, stream>>>(Wproj, wprojT, CC, CC);
  convert_x<<<MROWS * CC / (256*8), 256, 0, stream>>>(x, xb);
  // 1) qkv GEMM + scatter
  gemm_qkv<<<dim3(MROWS / BM, NC3 / BN), 256, 0, stream>>>(xb, wqkvT, qb, kb, vt);
  // 2) attention: mt (q 0..63, kv 64) and s (q 64..319, kv 320)
  attn_kernel<4><<<BB * HH, 256, 0, stream>>>(qb, kb, vt, ob);
  attn_kernel<20><<<BB * HH * 4, 256, 0, stream>>>(qb, kb, vt, ob);
  // 3) proj GEMM + bias
  gemm_proj<<<dim3(MROWS / BM, CC / BN), 256, 0, stream>>>(ob, wprojT, bproj, out);
}

// Round 9
// 228.026 us; speedup vs baseline: 1.3628x; 1.3114x over previous
//
#include <hip/hip_runtime.h>
#include <hip/hip_bf16.h>
#include <stdint.h>

// ---- problem constants ----
#define BB 64
#define NN 320
#define CC 768
#define HH 12
#define DH 64
#define NC3 2304
#define MROWS (BB*NN)   // 20480

typedef __attribute__((ext_vector_type(8))) short short8;
typedef __attribute__((ext_vector_type(4))) float f32x4;
typedef __attribute__((ext_vector_type(8))) __bf16 bf16x8;

union BF8U { short8 s; bf16x8 b; };
static __device__ __forceinline__ bf16x8 asbf(short8 v){ BF8U u; u.s = v; return u.b; }

#define MFMA16(a,b,c) __builtin_amdgcn_mfma_f32_16x16x32_bf16((a),(b),(c),0,0,0)

// async global->LDS, 16B per lane; LDS dest = wave-uniform base + lane*16
static __device__ __forceinline__ void gload16(const void* g, void* l){
  __builtin_amdgcn_global_load_lds(
      (const __attribute__((address_space(1))) void*)g,
      (__attribute__((address_space(3))) void*)l, 16, 0, 0);
}

// ------------------------------------------------------------------
// Kernel 0a: tiled transpose+convert  outT[n][k] = bf16(in[k][n])
// ------------------------------------------------------------------
__global__ __launch_bounds__(256) void convert_wT(
    const float* __restrict__ in, __hip_bfloat16* __restrict__ outT,
    int K, int Nc)
{
  __shared__ __hip_bfloat16 t[64][72];   // +8 pad
  const int n0 = blockIdx.x * 64, k0 = blockIdx.y * 64;
  const int tid = threadIdx.x;
  const int tx = tid & 15, ty = tid >> 4;          // 16 x 16

  #pragma unroll
  for (int i = 0; i < 4; ++i){
    int kl = ty + i * 16;
    float4 v = *reinterpret_cast<const float4*>(&in[(size_t)(k0 + kl) * Nc + n0 + tx * 4]);
    t[tx*4+0][kl] = __float2bfloat16(v.x);
    t[tx*4+1][kl] = __float2bfloat16(v.y);
    t[tx*4+2][kl] = __float2bfloat16(v.z);
    t[tx*4+3][kl] = __float2bfloat16(v.w);
  }
  __syncthreads();
  #pragma unroll
  for (int j = 0; j < 2; ++j){
    int nl = (tid >> 3) + j * 32;
    int kl = (tid & 7) * 8;
    short8 v = *reinterpret_cast<const short8*>(&t[nl][kl]);
    *reinterpret_cast<short8*>(&outT[(size_t)(n0 + nl) * K + k0 + kl]) = v;
  }
}

// ------------------------------------------------------------------
// Kernel 0b: convert x fp32 -> bf16 (row-major, same layout)
// ------------------------------------------------------------------
__global__ __launch_bounds__(256) void convert_x(
    const float* __restrict__ X, __hip_bfloat16* __restrict__ Xb)
{
  size_t i = ((size_t)blockIdx.x * 256 + threadIdx.x) * 8;
  float4 a = *reinterpret_cast<const float4*>(&X[i]);
  float4 b = *reinterpret_cast<const float4*>(&X[i + 4]);
  __hip_bfloat16 t[8] = {__float2bfloat16(a.x), __float2bfloat16(a.y),
                         __float2bfloat16(a.z), __float2bfloat16(a.w),
                         __float2bfloat16(b.x), __float2bfloat16(b.y),
                         __float2bfloat16(b.z), __float2bfloat16(b.w)};
  *reinterpret_cast<short8*>(&Xb[i]) = *reinterpret_cast<const short8*>(t);
}

// ------------------------------------------------------------------
// GEMM: 128x128 tile, BK=64, 4 waves, single-buffered 32KB LDS,
// launch_bounds(256,4) -> 4 blocks/CU co-resident (the r7 win).
// ------------------------------------------------------------------
#define BM 128
#define BN 128
#define BK 64
#define NT (CC/BK)   // 12

__global__ __launch_bounds__(256, 4) void gemm_qkv(
    const __hip_bfloat16* __restrict__ Xb,       // [20480][768]
    const __hip_bfloat16* __restrict__ WT,       // [2304][768]
    __hip_bfloat16* __restrict__ qb,
    __hip_bfloat16* __restrict__ kb,
    __hip_bfloat16* __restrict__ vt)
{
  __shared__ __hip_bfloat16 As[BM][BK];   // 16 KB, linear (gload_lds dest)
  __shared__ __hip_bfloat16 Bs[BN][BK];   // 16 KB
  const int tid = threadIdx.x;
  const int bm = blockIdx.x * BM;
  const int bn = blockIdx.y * BN;
  const int w = tid >> 6, lane = tid & 63;
  const int wr = w >> 1, wc = w & 1;
  const int l16 = lane & 15, lq = lane >> 4;
  const int srow = lane >> 3;                          // 0..7 within chunk
  const int scol = ((lane & 7) ^ srow) * 8;            // pre-swizzled global col (elems)
  const int rsw  = (l16 & 7) * 8;                      // read-side XOR (elems)

  f32x4 acc[4][4];
  #pragma unroll
  for (int i = 0; i < 4; ++i)
    #pragma unroll
    for (int j = 0; j < 4; ++j) acc[i][j] = (f32x4){0.f,0.f,0.f,0.f};

  for (int k0 = 0; k0 < CC; k0 += BK){
    #pragma unroll
    for (int it = 0; it < 4; ++it){
      int c = w * 4 + it;                 // 0..15, 8 rows per 1KB chunk
      int row = c * 8 + srow;
      gload16(&Xb[(size_t)(bm + row) * CC + k0 + scol], &As[0][0] + c * 512);
      gload16(&WT[(size_t)(bn + row) * CC + k0 + scol], &Bs[0][0] + c * 512);
    }
    __syncthreads();   // vmcnt(0) drain + barrier: tile ready
    #pragma unroll
    for (int kc = 0; kc < 2; ++kc){
      const int acol = (kc*32 + lq*8) ^ rsw;
      short8 bfr[4];
      #pragma unroll
      for (int ni = 0; ni < 4; ++ni)
        bfr[ni] = *reinterpret_cast<const short8*>(&Bs[wc*64 + ni*16 + l16][acol]);
      #pragma unroll
      for (int mi = 0; mi < 4; ++mi){
        short8 af = *reinterpret_cast<const short8*>(&As[wr*64 + mi*16 + l16][acol]);
        #pragma unroll
        for (int ni = 0; ni < 4; ++ni)
          acc[mi][ni] = MFMA16(asbf(af), asbf(bfr[ni]), acc[mi][ni]);
      }
    }
    __syncthreads();   // compute done before next stage overwrites
  }

  // epilogue: scatter bf16 to q / k / vT
  #pragma unroll
  for (int mi = 0; mi < 4; ++mi){
    #pragma unroll
    for (int ni = 0; ni < 4; ++ni){
      #pragma unroll
      for (int r = 0; r < 4; ++r){
        int row = bm + wr*64 + mi*16 + lq*4 + r;   // token index in [0,20480)
        int col = bn + wc*64 + ni*16 + l16;        // qkv col in [0,2304)
        float val = acc[mi][ni][r];
        int b = row / NN, n = row % NN;
        int s = col / CC, rem = col % CC;
        int h = rem >> 6, dh = rem & 63;
        int bh = b * HH + h;
        __hip_bfloat16 bv = __float2bfloat16(val);
        if (s == 0)      qb[((size_t)bh * NN + n) * DH + dh] = bv;
        else if (s == 1) kb[((size_t)bh * NN + n) * DH + dh] = bv;
        else             vt[((size_t)bh * DH + dh) * NN + n] = bv;
      }
    }
  }
}

// ------------------------------------------------------------------
// Kernel 2 (r9 rewrite): attention with cooperative K/V LDS staging.
// One block = (b,h) x 64 q-rows; 4 waves x 16 rows. KV processed in
// 64-wide tiles: K/V tiles staged via gload16 (double-buffered for
// NKT=20) with counted vmcnt(2) so the next tile's loads stay in
// flight across barriers (T3/T4 — this kernel IS latency-bound:
// r8 counters MfmaUtil 4.4%, VALU 16%, HBM 14%). P materialized
// tile-wise per wave (16x64). XOR swizzle both-sides on K/V tiles.
// ------------------------------------------------------------------
template<int NKT>
__global__ __launch_bounds__(256) void attn_kernel(
    const __hip_bfloat16* __restrict__ qb,
    const __hip_bfloat16* __restrict__ kb,
    const __hip_bfloat16* __restrict__ vt,
    __hip_bfloat16* __restrict__ ob)
{
  constexpr int NTILE = NKT / 4;              // 64-kv tiles: 5 (s) or 1 (mt)
  constexpr int NBUF  = (NTILE > 1) ? 2 : 1;
  __shared__ __hip_bfloat16 Kt[NBUF][64][64]; // 8KB per buf
  __shared__ __hip_bfloat16 Vt[NBUF][64][64];
  __shared__ __hip_bfloat16 P[4][16][72];     // per-wave P tile, +8 pad

  const int tid = threadIdx.x;
  const int w = tid >> 6, lane = tid & 63;
  const int l16 = lane & 15, lq = lane >> 4;
  const int srow = lane >> 3;                    // 0..7
  const int scol = ((lane & 7) ^ srow) * 8;      // pre-swizzled source col
  const int rsw  = (l16 & 7) * 8;                // read-side XOR

  int bh, qbase;
  if (NKT == 4){ bh = blockIdx.x;      qbase = 0; }
  else         { bh = blockIdx.x >> 2; qbase = 64 + (blockIdx.x & 3) * 64; }
  const int qrow0 = qbase + w * 16;

  const __hip_bfloat16* qp = qb + ((size_t)bh * NN + qrow0) * DH;
  const __hip_bfloat16* kp = kb + (size_t)bh * NN * DH;
  const __hip_bfloat16* vp = vt + (size_t)bh * DH * NN;

  // Q fragments (held for whole kernel); pin before staging
  short8 aq[2];
  #pragma unroll
  for (int kc = 0; kc < 2; ++kc)
    aq[kc] = *reinterpret_cast<const short8*>(&qp[l16 * DH + kc*32 + lq*8]);
  __builtin_amdgcn_sched_barrier(0);

  // K tile j: rows kv = j*64..+63 of kb[.][64] (128B rows); 8 chunks, 2/wave
  auto stageK = [&](int j){
    #pragma unroll
    for (int it = 0; it < 2; ++it){
      int c = w * 2 + it;
      gload16(&kp[(size_t)(j*64 + c*8 + srow) * DH + scol],
              &Kt[j & (NBUF-1)][0][0] + c * 512);
    }
  };
  // V tile j: rows d=0..63 of vt[.][320], cols j*64..+63
  auto stageV = [&](int j){
    #pragma unroll
    for (int it = 0; it < 2; ++it){
      int c = w * 2 + it;
      gload16(&vp[(size_t)(c*8 + srow) * NN + j*64 + scol],
              &Vt[j & (NBUF-1)][0][0] + c * 512);
    }
  };

  f32x4 s[NKT];
  #pragma unroll
  for (int kt = 0; kt < NKT; ++kt) s[kt] = (f32x4){0.f,0.f,0.f,0.f};

  // ---- Phase A: S = Q K^T over kv tiles ----
  stageK(0);
  if (NTILE > 1) stageK(1);
  #pragma unroll
  for (int j = 0; j < NTILE; ++j){
    if (j + 1 < NTILE) asm volatile("s_waitcnt vmcnt(2)" ::: "memory");
    else               asm volatile("s_waitcnt vmcnt(0)" ::: "memory");
    __builtin_amdgcn_s_barrier();              // tile j ready for all waves
    #pragma unroll
    for (int kc = 0; kc < 2; ++kc){
      const int acol = (kc*32 + lq*8) ^ rsw;
      #pragma unroll
      for (int ktl = 0; ktl < 4; ++ktl){
        short8 bk = *reinterpret_cast<const short8*>(&Kt[j & (NBUF-1)][ktl*16 + l16][acol]);
        s[j*4 + ktl] = MFMA16(asbf(aq[kc]), asbf(bk), s[j*4 + ktl]);
      }
    }
    __builtin_amdgcn_s_barrier();              // all waves done with tile j
    if (j + 2 < NTILE) stageK(j + 2);          // overwrite j's buffer (safe)
  }

  // prefetch V tiles 0(,1) — latency hides under softmax
  stageV(0);
  if (NTILE > 1) stageV(1);

  // ---- softmax over KV cols (rows lq*4+r); logits = s * 0.125 ----
  const float scale = 0.125f;
  float sum[4];
  #pragma unroll
  for (int r = 0; r < 4; ++r){
    float mx = -1e30f;
    #pragma unroll
    for (int kt = 0; kt < NKT; ++kt) mx = fmaxf(mx, s[kt][r]);
    #pragma unroll
    for (int off = 1; off < 16; off <<= 1) mx = fmaxf(mx, __shfl_xor(mx, off));
    float sm = 0.f;
    #pragma unroll
    for (int kt = 0; kt < NKT; ++kt){
      float p = __expf((s[kt][r] - mx) * scale);
      __hip_bfloat16 pb = __float2bfloat16(p);
      s[kt][r] = __bfloat162float(pb);         // keep bf16-rounded p in regs
      sm += __bfloat162float(pb);              // denominator consistent with P
    }
    #pragma unroll
    for (int off = 1; off < 16; off <<= 1) sm += __shfl_xor(sm, off);
    sum[r] = sm;
  }

  // ---- Phase B: O = P V over kv tiles ----
  f32x4 o[4];
  #pragma unroll
  for (int nt = 0; nt < 4; ++nt) o[nt] = (f32x4){0.f,0.f,0.f,0.f};
  #pragma unroll
  for (int j = 0; j < NTILE; ++j){
    if (j + 1 < NTILE) asm volatile("s_waitcnt vmcnt(2)" ::: "memory");
    else               asm volatile("s_waitcnt vmcnt(0)" ::: "memory");
    __builtin_amdgcn_s_barrier();              // V tile j ready
    // write this wave's P tile (16 x 64)
    #pragma unroll
    for (int ktl = 0; ktl < 4; ++ktl)
      #pragma unroll
      for (int r = 0; r < 4; ++r)
        P[w][lq*4 + r][ktl*16 + l16] = __float2bfloat16(s[j*4 + ktl][r]);
    #pragma unroll
    for (int kc = 0; kc < 2; ++kc){
      short8 ap = *reinterpret_cast<const short8*>(&P[w][l16][kc*32 + lq*8]);
      const int vcol = (kc*32 + lq*8) ^ rsw;
      #pragma unroll
      for (int nt = 0; nt < 4; ++nt){
        short8 bv = *reinterpret_cast<const short8*>(&Vt[j & (NBUF-1)][nt*16 + l16][vcol]);
        o[nt] = MFMA16(asbf(ap), asbf(bv), o[nt]);
      }
    }
    __builtin_amdgcn_s_barrier();              // all waves done with V tile j
    if (j + 2 < NTILE) stageV(j + 2);
  }

  // write o / sum -> ob[b*320 + qrow][h*64 + dh]
  const int b = bh / HH, h = bh % HH;
  #pragma unroll
  for (int nt = 0; nt < 4; ++nt){
    #pragma unroll
    for (int r = 0; r < 4; ++r){
      int qrow = qrow0 + lq*4 + r;
      int dh = nt*16 + l16;
      float val = o[nt][r] / sum[r];
      ob[((size_t)b * NN + qrow) * CC + h * DH + dh] = __float2bfloat16(val);
    }
  }
}

// ------------------------------------------------------------------
// Kernel 3: proj GEMM (M=20480, K=768, N=768) + bias, fp32 out.
// ------------------------------------------------------------------
__global__ __launch_bounds__(256, 4) void gemm_proj(
    const __hip_bfloat16* __restrict__ A,        // [20480][768] bf16
    const __hip_bfloat16* __restrict__ WT,       // [768][768] bf16 (transposed)
    const float* __restrict__ bias,
    float* __restrict__ out)
{
  __shared__ __hip_bfloat16 As[BM][BK];
  __shared__ __hip_bfloat16 Bs[BN][BK];
  const int tid = threadIdx.x;
  const int bm = blockIdx.x * BM;
  const int bn = blockIdx.y * BN;
  const int w = tid >> 6, lane = tid & 63;
  const int wr = w >> 1, wc = w & 1;
  const int l16 = lane & 15, lq = lane >> 4;
  const int srow = lane >> 3;
  const int scol = ((lane & 7) ^ srow) * 8;
  const int rsw  = (l16 & 7) * 8;

  f32x4 acc[4][4];
  #pragma unroll
  for (int i = 0; i < 4; ++i)
    #pragma unroll
    for (int j = 0; j < 4; ++j) acc[i][j] = (f32x4){0.f,0.f,0.f,0.f};

  for (int k0 = 0; k0 < CC; k0 += BK){
    #pragma unroll
    for (int it = 0; it < 4; ++it){
      int c = w * 4 + it;
      int row = c * 8 + srow;
      gload16(&A [(size_t)(bm + row) * CC + k0 + scol], &As[0][0] + c * 512);
      gload16(&WT[(size_t)(bn + row) * CC + k0 + scol], &Bs[0][0] + c * 512);
    }
    __syncthreads();
    #pragma unroll
    for (int kc = 0; kc < 2; ++kc){
      const int acol = (kc*32 + lq*8) ^ rsw;
      short8 bfr[4];
      #pragma unroll
      for (int ni = 0; ni < 4; ++ni)
        bfr[ni] = *reinterpret_cast<const short8*>(&Bs[wc*64 + ni*16 + l16][acol]);
      #pragma unroll
      for (int mi = 0; mi < 4; ++mi){
        short8 af = *reinterpret_cast<const short8*>(&As[wr*64 + mi*16 + l16][acol]);
        #pragma unroll
        for (int ni = 0; ni < 4; ++ni)
          acc[mi][ni] = MFMA16(asbf(af), asbf(bfr[ni]), acc[mi][ni]);
      }
    }
    __syncthreads();
  }

  #pragma unroll
  for (int mi = 0; mi < 4; ++mi){
    #pragma unroll
    for (int ni = 0; ni < 4; ++ni){
      #pragma unroll
      for (int r = 0; r < 4; ++r){
        int row = bm + wr*64 + mi*16 + lq*4 + r;
        int col = bn + wc*64 + ni*16 + l16;
        out[(size_t)row * CC + col] = acc[mi][ni][r] + bias[col];
      }
    }
  }
}

// ------------------------------------------------------------------
extern "C" void kernel_launch(void* const* d_in, const int* in_sizes, int n_in,
                              void* d_out, int out_size, void* d_ws, size_t ws_size,
                              hipStream_t stream)
{
  const float* x     = (const float*)d_in[0];
  const float* Wqkv  = (const float*)d_in[1];
  const float* Wproj = (const float*)d_in[2];
  const float* bproj = (const float*)d_in[3];
  float* out = (float*)d_out;

  char* ws = (char*)d_ws;
  __hip_bfloat16* wqkvT  = (__hip_bfloat16*)ws; ws += (size_t)NC3 * CC * 2;      // 3.54 MB
  __hip_bfloat16* wprojT = (__hip_bfloat16*)ws; ws += (size_t)CC * CC * 2;       // 1.18 MB
  __hip_bfloat16* xb     = (__hip_bfloat16*)ws; ws += (size_t)MROWS * CC * 2;    // 31.46 MB
  const size_t headsz = (size_t)BB * HH * NN * DH * 2;                           // 31.46 MB
  __hip_bfloat16* qb = (__hip_bfloat16*)ws; ws += headsz;
  __hip_bfloat16* kb = (__hip_bfloat16*)ws; ws += headsz;
  __hip_bfloat16* vt = (__hip_bfloat16*)ws; ws += headsz;
  __hip_bfloat16* ob = (__hip_bfloat16*)ws; ws += headsz;

  // 0) weights + x -> bf16
  convert_wT<<<dim3(NC3/64, CC/64), 256, 0, stream>>>(Wqkv, wqkvT, CC, NC3);
  convert_wT<<<dim3(CC/64,  CC/64), 256, 0, stream>>>(Wproj, wprojT, CC, CC);
  convert_x<<<MROWS * CC / (256*8), 256, 0, stream>>>(x, xb);
  // 1) qkv GEMM + scatter
  gemm_qkv<<<dim3(MROWS / BM, NC3 / BN), 256, 0, stream>>>(xb, wqkvT, qb, kb, vt);
  // 2) attention: mt (q 0..63, kv 64) and s (q 64..319, kv 320)
  attn_kernel<4><<<BB * HH, 256, 0, stream>>>(qb, kb, vt, ob);
  attn_kernel<20><<<BB * HH * 4, 256, 0, stream>>>(qb, kb, vt, ob);
  // 3) proj GEMM + bias
  gemm_proj<<<dim3(MROWS / BM, CC / BN), 256, 0, stream>>>(ob, wprojT, bproj, out);
}